// Round 7
// baseline (221.048 us; speedup 1.0000x reference)
//
#include <hip/hip_runtime.h>
#include <hip/hip_bf16.h>

#define NB 4
#define SEQ 1024
#define DMODEL 1024
#define NH 16
#define DH 64
#define SCALE_F 0.125f
#define QSCALE 0.18033688011112042f   // SCALE_F * log2(e): folds exp->exp2
#define ZTH 1.5f

typedef __bf16 bf16x8 __attribute__((ext_vector_type(8)));
typedef float f32x4 __attribute__((ext_vector_type(4)));
typedef unsigned short u16;
typedef unsigned int u32;

__device__ __forceinline__ u32 bf16_rne(float f) {
    u32 u = __float_as_uint(f);
    return (u + 0x7fffu + ((u >> 16) & 1u)) >> 16;
}
__device__ __forceinline__ u32 pk2(float a, float b) {   // low u16 = a
    return bf16_rne(a) | (bf16_rne(b) << 16);
}

// ---------------------------------------------------------------------------
// Fused precision-convert: x -> hi/lo, w_qkv -> hi/lo, w_out -> bf16.
// One launch replaces three (fewer launch gaps).
// ---------------------------------------------------------------------------
#define N8_X   (NB * SEQ * DMODEL / 8)            // 524288
#define N8_WQ  (3 * DMODEL * DMODEL / 8)          // 393216
#define N8_WO  (DMODEL * DMODEL / 8)              // 131072

__global__ __launch_bounds__(256)
void convert_all(const float* __restrict__ x,  u16* __restrict__ xh,  u16* __restrict__ xl,
                 const float* __restrict__ wq, u16* __restrict__ wqh, u16* __restrict__ wql,
                 const float* __restrict__ wo, u16* __restrict__ wob)
{
    int i = blockIdx.x * 256 + threadIdx.x;
    const float* src;
    u16 *hi, *lo;
    int j;
    if (i < N8_X)            { src = x;  hi = xh;  lo = xl;  j = i; }
    else if (i < N8_X + N8_WQ) { src = wq; hi = wqh; lo = wql; j = i - N8_X; }
    else {                     // w_out: single bf16
        j = i - N8_X - N8_WQ;
        if (j >= N8_WO) return;
        const float4* p = (const float4*)wo + (size_t)j * 2;
        float4 v0 = p[0], v1 = p[1];
        uint4 o;
        o.x = pk2(v0.x, v0.y); o.y = pk2(v0.z, v0.w);
        o.z = pk2(v1.x, v1.y); o.w = pk2(v1.z, v1.w);
        ((uint4*)wob)[j] = o;
        return;
    }
    const float4* p = (const float4*)src + (size_t)j * 2;
    float4 v0 = p[0], v1 = p[1];
    float f[8] = {v0.x, v0.y, v0.z, v0.w, v1.x, v1.y, v1.z, v1.w};
    u32 h[8], l[8];
    #pragma unroll
    for (int t = 0; t < 8; ++t) {
        u32 u = __float_as_uint(f[t]);
        u32 rh = (u + 0x7fffu + ((u >> 16) & 1u)) & 0xffff0000u;
        h[t] = rh >> 16;
        l[t] = bf16_rne(f[t] - __uint_as_float(rh));
    }
    uint4 ho, lw;
    ho.x = h[0] | (h[1] << 16); ho.y = h[2] | (h[3] << 16);
    ho.z = h[4] | (h[5] << 16); ho.w = h[6] | (h[7] << 16);
    lw.x = l[0] | (l[1] << 16); lw.y = l[2] | (l[3] << 16);
    lw.z = l[4] | (l[5] << 16); lw.w = l[6] | (l[7] << 16);
    ((uint4*)hi)[j] = ho;
    ((uint4*)lo)[j] = lw;
}

// ---------------------------------------------------------------------------
// MFMA GEMM: C = A * B^T, bf16 hi/lo split.
// MODE 0: QKV.  Q/K tiles: 3-term split.  V tiles (nBase>=2048): 1-term
//         (V is bf16-rounded in the epilogue anyway; V never feeds the mask)
//         -> those blocks skip Al/Bl staging (half the fetch) + 2/3 the MFMA.
// MODE 1: out-proj, 1-term; fp32 row-major + bias.
// 128x128 tile, BK=32, 4 waves, 3 blocks/CU.
// ---------------------------------------------------------------------------
template<int MODE>
__global__ __launch_bounds__(256, 3)
void gemm_split(const u16* __restrict__ Ah, const u16* __restrict__ Al,
                const u16* __restrict__ Bh, const u16* __restrict__ Bl,
                const float* __restrict__ bias,
                u16* __restrict__ Qh, u16* __restrict__ Ql,
                u16* __restrict__ Kh, u16* __restrict__ Kl,
                u16* __restrict__ Vt, float* __restrict__ Cout)
{
    constexpr int M = NB * SEQ;
    constexpr int NCOL = (MODE == 0) ? 3 * DMODEL : DMODEL;
    constexpr int K = DMODEL;
    constexpr int NTN = NCOL / 128;
    constexpr int NWG = (M / 128) * NTN;
    constexpr int NT = (MODE == 0) ? 4 : 2;

    __shared__ u16 lds[NT][4][128][8];

    const int tid = threadIdx.x;
    const int bid = blockIdx.x;
    const int swz = (bid & 7) * (NWG >> 3) + (bid >> 3);
    const int mBase = (swz / NTN) * 128;
    const int nBase = (swz % NTN) * 128;
    // 3-term split only where precision matters (Q/K tiles); V tiles 1-term.
    const bool t3 = (MODE == 0) && (nBase < 2 * DMODEL);

    const int wave = tid >> 6, lane = tid & 63;
    const int wr = wave >> 1, wc = wave & 1;
    const int rsel = lane & 15, ks = lane >> 4;

    const int r0 = tid >> 2, c0 = tid & 3;
    const size_t aoff0 = (size_t)(mBase + r0) * K + c0 * 8;
    const size_t aoff1 = (size_t)(mBase + 64 + r0) * K + c0 * 8;
    const size_t boff0 = (size_t)(nBase + r0) * K + c0 * 8;
    const size_t boff1 = (size_t)(nBase + 64 + r0) * K + c0 * 8;
    const int wrow0 = r0 ^ c0, wrow1 = (r0 ^ c0) + 64;

    const bf16x8 *rAh[4], *rAl[4], *rBh[4], *rBl[4];
    #pragma unroll
    for (int m = 0; m < 4; ++m) {
        int ar = (wr * 64 + m * 16 + rsel) ^ ks;
        rAh[m] = (const bf16x8*)&lds[0][ks][ar][0];
        if constexpr (MODE == 0) rAl[m] = (const bf16x8*)&lds[2][ks][ar][0];
    }
    #pragma unroll
    for (int n = 0; n < 4; ++n) {
        int bc = (wc * 64 + n * 16 + rsel) ^ ks;
        rBh[n] = (const bf16x8*)&lds[1][ks][bc][0];
        if constexpr (MODE == 0) rBl[n] = (const bf16x8*)&lds[3][ks][bc][0];
    }

    f32x4 acc[4][4];
    #pragma unroll
    for (int m = 0; m < 4; ++m)
        #pragma unroll
        for (int n = 0; n < 4; ++n)
            acc[m][n] = (f32x4)0.0f;

    uint4 sAh0, sAh1, sAl0, sAl1, sBh0, sBh1, sBl0, sBl1;
    #define LOADS(k0)                                                       \
        sAh0 = *(const uint4*)(Ah + aoff0 + (k0));                          \
        sAh1 = *(const uint4*)(Ah + aoff1 + (k0));                          \
        sBh0 = *(const uint4*)(Bh + boff0 + (k0));                          \
        sBh1 = *(const uint4*)(Bh + boff1 + (k0));                          \
        if (t3) {                                                           \
            sAl0 = *(const uint4*)(Al + aoff0 + (k0));                      \
            sAl1 = *(const uint4*)(Al + aoff1 + (k0));                      \
            sBl0 = *(const uint4*)(Bl + boff0 + (k0));                      \
            sBl1 = *(const uint4*)(Bl + boff1 + (k0));                      \
        }

    LOADS(0)

    for (int it = 0; it < K / 32; ++it) {
        __syncthreads();
        *(uint4*)&lds[0][c0][wrow0][0] = sAh0;
        *(uint4*)&lds[0][c0][wrow1][0] = sAh1;
        *(uint4*)&lds[1][c0][wrow0][0] = sBh0;
        *(uint4*)&lds[1][c0][wrow1][0] = sBh1;
        if (t3) {
            *(uint4*)&lds[2][c0][wrow0][0] = sAl0;
            *(uint4*)&lds[2][c0][wrow1][0] = sAl1;
            *(uint4*)&lds[3][c0][wrow0][0] = sBl0;
            *(uint4*)&lds[3][c0][wrow1][0] = sBl1;
        }
        __syncthreads();
        if (it < K / 32 - 1) {
            int k0 = (it + 1) * 32;
            LOADS(k0)
        }
        bf16x8 ah[4], bh[4], al[4], bl[4];
        #pragma unroll
        for (int m = 0; m < 4; ++m) { ah[m] = *rAh[m]; if (t3) al[m] = *rAl[m]; }
        #pragma unroll
        for (int n = 0; n < 4; ++n) { bh[n] = *rBh[n]; if (t3) bl[n] = *rBl[n]; }
        #pragma unroll
        for (int m = 0; m < 4; ++m)
            #pragma unroll
            for (int n = 0; n < 4; ++n) {
                acc[m][n] = __builtin_amdgcn_mfma_f32_16x16x32_bf16(ah[m], bh[n], acc[m][n], 0, 0, 0);
                if (t3) {
                    acc[m][n] = __builtin_amdgcn_mfma_f32_16x16x32_bf16(ah[m], bl[n], acc[m][n], 0, 0, 0);
                    acc[m][n] = __builtin_amdgcn_mfma_f32_16x16x32_bf16(al[m], bh[n], acc[m][n], 0, 0, 0);
                }
            }
    }
    #undef LOADS

    const int rowq = lane >> 4;
    #pragma unroll
    for (int m = 0; m < 4; ++m) {
        #pragma unroll
        for (int n = 0; n < 4; ++n) {
            int grow0 = mBase + wr * 64 + m * 16 + rowq * 4;
            int gcol  = nBase + wc * 64 + n * 16 + rsel;
            if constexpr (MODE == 0) {
                int which = gcol >> 10, h = (gcol >> 6) & 15, d = gcol & 63;
                if (which == 2) {
                    int b = grow0 >> 10, tok0 = grow0 & 1023;
                    ushort4 vv;
                    vv.x = (u16)bf16_rne(acc[m][n][0]);
                    vv.y = (u16)bf16_rne(acc[m][n][1]);
                    vv.z = (u16)bf16_rne(acc[m][n][2]);
                    vv.w = (u16)bf16_rne(acc[m][n][3]);
                    *(ushort4*)&Vt[((size_t)(b * NH + h) * DH + d) * SEQ + tok0] = vv;
                } else {
                    u16* Ph = (which == 0) ? Qh : Kh;
                    u16* Pl = (which == 0) ? Ql : Kl;
                    const float sc = (which == 0) ? QSCALE : 1.0f;
                    #pragma unroll
                    for (int r = 0; r < 4; ++r) {
                        int grow = grow0 + r;
                        int b = grow >> 10, tok = grow & 1023;
                        size_t idx = ((size_t)(b * NH + h) * SEQ + tok) * DH + d;
                        float f = acc[m][n][r] * sc;
                        u32 u = __float_as_uint(f);
                        u32 rh = (u + 0x7fffu + ((u >> 16) & 1u)) & 0xffff0000u;
                        Ph[idx] = (u16)(rh >> 16);
                        Pl[idx] = (u16)bf16_rne(f - __uint_as_float(rh));
                    }
                }
            } else {
                float bb = bias[gcol];
                #pragma unroll
                for (int r = 0; r < 4; ++r)
                    Cout[(size_t)(grow0 + r) * NCOL + gcol] = acc[m][n][r] + bb;
            }
        }
    }
}

// ---------------------------------------------------------------------------
// Pass 1 (unchanged from R6): diag of softmax(dots), LDS-shared K chunks.
// ---------------------------------------------------------------------------
__global__ __launch_bounds__(256)
void attn_pass1_mfma(const u16* __restrict__ qhp, const u16* __restrict__ qlp,
                     const u16* __restrict__ khp, const u16* __restrict__ klp,
                     float* __restrict__ diag)
{
    __shared__ u16 Ks[64][64];
    __shared__ u16 Kl[64][64];
    const int bh = blockIdx.x;
    const int tid = threadIdx.x;
    const int wid = tid >> 6, lane = tid & 63;
    const int qloc = lane & 15, quad = lane >> 4;
    const int qbase = blockIdx.y * 128 + wid * 32;
    const size_t base = (size_t)bh * SEQ;

    bf16x8 qbh[2][2], qbl[2][2];
    #pragma unroll
    for (int qf = 0; qf < 2; ++qf)
        #pragma unroll
        for (int dc = 0; dc < 2; ++dc) {
            size_t off = (base + qbase + qf * 16 + qloc) * DH + dc * 32 + quad * 8;
            qbh[qf][dc] = *(const bf16x8*)(qhp + off);
            qbl[qf][dc] = *(const bf16x8*)(qlp + off);
        }

    const int r0 = tid >> 3, s0 = tid & 7, r1 = r0 + 32;
    const int ws0 = (s0 ^ (r0 & 7)) * 8;
    const int ws1 = (s0 ^ (r1 & 7)) * 8;
    const u16* kb = khp + base * DH;
    const u16* lb = klp + base * DH;

    int aoff[4][2];
    #pragma unroll
    for (int t = 0; t < 4; ++t)
        #pragma unroll
        for (int dc = 0; dc < 2; ++dc)
            aoff[t][dc] = (t * 16 + qloc) * 128 + (((dc * 4 + quad) ^ (qloc & 7)) << 4);

    float lsum[2] = {0.f, 0.f}, sd[2] = {0.f, 0.f};
    const int dcb  = qbase & ~63;
    const int toff = (qbase & 32) >> 4;

    uint4 gk0, gk1, gl0, gl1;
    #define P1LOAD(cb)                                                      \
        gk0 = *(const uint4*)(kb + (size_t)((cb) + r0) * DH + s0 * 8);      \
        gk1 = *(const uint4*)(kb + (size_t)((cb) + r1) * DH + s0 * 8);      \
        gl0 = *(const uint4*)(lb + (size_t)((cb) + r0) * DH + s0 * 8);      \
        gl1 = *(const uint4*)(lb + (size_t)((cb) + r1) * DH + s0 * 8);

    P1LOAD(0)
    for (int it = 0; it < SEQ / 64; ++it) {
        __syncthreads();
        *(uint4*)&Ks[r0][ws0] = gk0;
        *(uint4*)&Ks[r1][ws1] = gk1;
        *(uint4*)&Kl[r0][ws0] = gl0;
        *(uint4*)&Kl[r1][ws1] = gl1;
        __syncthreads();
        if (it < SEQ / 64 - 1) { P1LOAD((it + 1) * 64) }

        const int cb = it * 64;
        const bool dchunk = (cb == dcb);
        bf16x8 ah[4][2], al[4][2];
        #pragma unroll
        for (int t = 0; t < 4; ++t)
            #pragma unroll
            for (int dc = 0; dc < 2; ++dc) {
                ah[t][dc] = *(const bf16x8*)((const char*)&Ks[0][0] + aoff[t][dc]);
                al[t][dc] = *(const bf16x8*)((const char*)&Kl[0][0] + aoff[t][dc]);
            }
        #pragma unroll
        for (int qf = 0; qf < 2; ++qf)
            #pragma unroll
            for (int t = 0; t < 4; ++t) {
                f32x4 d = (f32x4)0.f;
                #pragma unroll
                for (int dc = 0; dc < 2; ++dc) {
                    d = __builtin_amdgcn_mfma_f32_16x16x32_bf16(ah[t][dc], qbh[qf][dc], d, 0, 0, 0);
                    d = __builtin_amdgcn_mfma_f32_16x16x32_bf16(ah[t][dc], qbl[qf][dc], d, 0, 0, 0);
                    d = __builtin_amdgcn_mfma_f32_16x16x32_bf16(al[t][dc], qbh[qf][dc], d, 0, 0, 0);
                }
                if (dchunk) {
                    #pragma unroll
                    for (int dc = 0; dc < 2; ++dc)
                        d = __builtin_amdgcn_mfma_f32_16x16x32_bf16(al[t][dc], qbl[qf][dc], d, 0, 0, 0);
                }
                #pragma unroll
                for (int r = 0; r < 4; ++r) {
                    float ex = exp2f(d[r]);
                    lsum[qf] += ex;
                    if (dchunk && t == toff + qf && quad == (qloc >> 2) && r == (qloc & 3))
                        sd[qf] = ex;
                }
            }
    }
    #undef P1LOAD

    #pragma unroll
    for (int qf = 0; qf < 2; ++qf) {
        lsum[qf] += __shfl_xor(lsum[qf], 16);
        lsum[qf] += __shfl_xor(lsum[qf], 32);
        sd[qf]   += __shfl_xor(sd[qf], 16);
        sd[qf]   += __shfl_xor(sd[qf], 32);
    }
    if (quad == 0) {
        diag[base + qbase + qloc]      = sd[0] / lsum[0];
        diag[base + qbase + 16 + qloc] = sd[1] / lsum[1];
    }
}

// ---------------------------------------------------------------------------
// Per-(b,h) z-score mask -> float 0/1 (unchanged).
// ---------------------------------------------------------------------------
__global__ __launch_bounds__(256)
void mask_stats(const float* __restrict__ diag, float* __restrict__ keepf)
{
    __shared__ float red[256];
    const int bh = blockIdx.x, tid = threadIdx.x;
    const float* d = diag + (size_t)bh * SEQ;
    float4 v = *(const float4*)(d + tid * 4);
    red[tid] = (v.x + v.y) + (v.z + v.w);
    __syncthreads();
    for (int w = 128; w > 0; w >>= 1) {
        if (tid < w) red[tid] += red[tid + w];
        __syncthreads();
    }
    float mu = red[0] * (1.0f / 1024.0f);
    __syncthreads();
    float dx0 = v.x - mu, dx1 = v.y - mu, dx2 = v.z - mu, dx3 = v.w - mu;
    red[tid] = (dx0 * dx0 + dx1 * dx1) + (dx2 * dx2 + dx3 * dx3);
    __syncthreads();
    for (int w = 128; w > 0; w >>= 1) {
        if (tid < w) red[tid] += red[tid + w];
        __syncthreads();
    }
    float sd = sqrtf(red[0] * (1.0f / 1023.0f));
    float4 kv;
    kv.x = (fabsf(dx0 / sd) <= ZTH) ? 1.f : 0.f;
    kv.y = (fabsf(dx1 / sd) <= ZTH) ? 1.f : 0.f;
    kv.z = (fabsf(dx2 / sd) <= ZTH) ? 1.f : 0.f;
    kv.w = (fabsf(dx3 / sd) <= ZTH) ? 1.f : 0.f;
    *(float4*)&keepf[(size_t)bh * SEQ + tid * 4] = kv;
}

// ---------------------------------------------------------------------------
// Pass 2 (unchanged from R6): masked softmax + PV, LDS-shared K/V chunks.
// ---------------------------------------------------------------------------
__global__ __launch_bounds__(256)
void attn_pass2_mfma(const u16* __restrict__ qhp, const u16* __restrict__ khp,
                     const u16* __restrict__ vTp, const float* __restrict__ keepf,
                     u16* __restrict__ att)
{
    __shared__ u16 Ks[64][64];
    __shared__ u16 Vs[64][64];
    __shared__ u16 P[4][32][64];
    const int bh = blockIdx.x;
    const int b = bh >> 4, h = bh & 15;
    const int tid = threadIdx.x;
    const int wid = tid >> 6, lane = tid & 63;
    const int qloc = lane & 15, quad = lane >> 4;
    const int qbase = blockIdx.y * 128 + wid * 32;
    const size_t base = (size_t)bh * SEQ;

    bf16x8 qb[2][2];
    #pragma unroll
    for (int qf = 0; qf < 2; ++qf)
        #pragma unroll
        for (int dc = 0; dc < 2; ++dc)
            qb[qf][dc] = *(const bf16x8*)(qhp + (base + qbase + qf * 16 + qloc) * DH + dc * 32 + quad * 8);

    const float rkf[2] = {keepf[base + qbase + qloc],
                          keepf[base + qbase + 16 + qloc]};

    const int r0 = tid >> 3, s0 = tid & 7, r1 = r0 + 32;
    const int ws0 = (s0 ^ (r0 & 7)) * 8;
    const int ws1 = (s0 ^ (r1 & 7)) * 8;
    const u16* kb = khp + base * DH;
    const u16* vb = vTp + (size_t)bh * DH * SEQ;

    int aoff[4][2], voff[4][2];
    #pragma unroll
    for (int t = 0; t < 4; ++t)
        #pragma unroll
        for (int dc = 0; dc < 2; ++dc)
            aoff[t][dc] = (t * 16 + qloc) * 128 + (((dc * 4 + quad) ^ (qloc & 7)) << 4);
    #pragma unroll
    for (int dt = 0; dt < 4; ++dt)
        #pragma unroll
        for (int c = 0; c < 2; ++c)
            voff[dt][c] = (dt * 16 + qloc) * 128 + (((c * 4 + quad) ^ (qloc & 7)) << 4);

    char* Pw = (char*)&P[wid][0][0];
    int woff[2][4], roff[2][2];
    #pragma unroll
    for (int qf = 0; qf < 2; ++qf) {
        int row = qf * 16 + qloc;
        #pragma unroll
        for (int t = 0; t < 4; ++t) {
            int g = t * 2 + (quad >> 1);
            woff[qf][t] = row * 128 + ((g ^ (qloc & 7)) << 4) + (quad & 1) * 8;
        }
        #pragma unroll
        for (int c = 0; c < 2; ++c) {
            int g = c * 4 + quad;
            roff[qf][c] = row * 128 + ((g ^ (qloc & 7)) << 4);
        }
    }

    f32x4 acc2[2][4];
    #pragma unroll
    for (int qf = 0; qf < 2; ++qf)
        #pragma unroll
        for (int dt = 0; dt < 4; ++dt)
            acc2[qf][dt] = (f32x4)0.f;
    float lsum[2] = {0.f, 0.f};

    uint4 gk0, gk1, gv0, gv1;
    #define P2LOAD(cb)                                                      \
        gk0 = *(const uint4*)(kb + (size_t)((cb) + r0) * DH + s0 * 8);      \
        gk1 = *(const uint4*)(kb + (size_t)((cb) + r1) * DH + s0 * 8);      \
        gv0 = *(const uint4*)(vb + (size_t)r0 * SEQ + (cb) + s0 * 8);       \
        gv1 = *(const uint4*)(vb + (size_t)r1 * SEQ + (cb) + s0 * 8);

    P2LOAD(0)
    for (int it = 0; it < SEQ / 64; ++it) {
        __syncthreads();
        *(uint4*)&Ks[r0][ws0] = gk0;
        *(uint4*)&Ks[r1][ws1] = gk1;
        *(uint4*)&Vs[r0][ws0] = gv0;
        *(uint4*)&Vs[r1][ws1] = gv1;
        __syncthreads();
        if (it < SEQ / 64 - 1) { P2LOAD((it + 1) * 64) }

        const int cb = it * 64;
        bf16x8 ah[4][2], va[4][2];
        #pragma unroll
        for (int t = 0; t < 4; ++t)
            #pragma unroll
            for (int dc = 0; dc < 2; ++dc)
                ah[t][dc] = *(const bf16x8*)((const char*)&Ks[0][0] + aoff[t][dc]);
        #pragma unroll
        for (int dt = 0; dt < 4; ++dt)
            #pragma unroll
            for (int c = 0; c < 2; ++c)
                va[dt][c] = *(const bf16x8*)((const char*)&Vs[0][0] + voff[dt][c]);

        float4 kf[4];
        #pragma unroll
        for (int t = 0; t < 4; ++t)
            kf[t] = *(const float4*)(keepf + base + cb + t * 16 + quad * 4);

        #pragma unroll
        for (int qf = 0; qf < 2; ++qf)
            #pragma unroll
            for (int t = 0; t < 4; ++t) {
                f32x4 d = (f32x4)0.f;
                d = __builtin_amdgcn_mfma_f32_16x16x32_bf16(ah[t][0], qb[qf][0], d, 0, 0, 0);
                d = __builtin_amdgcn_mfma_f32_16x16x32_bf16(ah[t][1], qb[qf][1], d, 0, 0, 0);
                float p0 = exp2f(d[0]) * kf[t].x;
                float p1 = exp2f(d[1]) * kf[t].y;
                float p2 = exp2f(d[2]) * kf[t].z;
                float p3 = exp2f(d[3]) * kf[t].w;
                lsum[qf] += (p0 + p1) + (p2 + p3);
                uint2 w;
                asm("v_cvt_pk_bf16_f32 %0, %1, %2" : "=v"(w.x) : "v"(p0), "v"(p1));
                asm("v_cvt_pk_bf16_f32 %0, %1, %2" : "=v"(w.y) : "v"(p2), "v"(p3));
                *(uint2*)(Pw + woff[qf][t]) = w;
            }

        #pragma unroll
        for (int qf = 0; qf < 2; ++qf) {
            #pragma unroll
            for (int c = 0; c < 2; ++c) {
                bf16x8 pb = *(const bf16x8*)(Pw + roff[qf][c]);
                #pragma unroll
                for (int dt = 0; dt < 4; ++dt)
                    acc2[qf][dt] = __builtin_amdgcn_mfma_f32_16x16x32_bf16(va[dt][c], pb, acc2[qf][dt], 0, 0, 0);
            }
        }
    }
    #undef P2LOAD

    #pragma unroll
    for (int qf = 0; qf < 2; ++qf) {
        lsum[qf] += __shfl_xor(lsum[qf], 16);
        lsum[qf] += __shfl_xor(lsum[qf], 32);
        float inv = rkf[qf] / fmaxf(lsum[qf], 1e-30f);
        int tok = qbase + qf * 16 + qloc;
        #pragma unroll
        for (int dt = 0; dt < 4; ++dt) {
            uint2 w;
            w.x = pk2(acc2[qf][dt][0] * inv, acc2[qf][dt][1] * inv);
            w.y = pk2(acc2[qf][dt][2] * inv, acc2[qf][dt][3] * inv);
            *(uint2*)&att[((size_t)(b * SEQ + tok)) * DMODEL + h * DH + dt * 16 + quad * 4] = w;
        }
    }
}

// ---------------------------------------------------------------------------
extern "C" void kernel_launch(void* const* d_in, const int* in_sizes, int n_in,
                              void* d_out, int out_size, void* d_ws, size_t ws_size,
                              hipStream_t stream)
{
    const float* x     = (const float*)d_in[0];
    const float* w_qkv = (const float*)d_in[1];
    const float* w_out = (const float*)d_in[2];
    const float* b_out = (const float*)d_in[3];
    float* out = (float*)d_out;

    char* ws = (char*)d_ws;
    const size_t T = (size_t)NB * NH * SEQ * DH * sizeof(u16);   // 8 MB per head-tensor

    u16* qh   = (u16*)(ws);
    u16* ql   = (u16*)(ws + T);
    u16* kh   = (u16*)(ws + 2 * T);
    u16* kl   = (u16*)(ws + 3 * T);
    u16* vT   = (u16*)(ws + 4 * T);
    u16* attb = (u16*)(ws + 5 * T);
    u16* wob  = (u16*)(ws + 6 * T);                               // 2 MB
    float* diag  = (float*)(ws + 6 * T + (size_t)DMODEL * DMODEL * sizeof(u16));
    float* keepf = (float*)((char*)diag + (size_t)NB * NH * SEQ * sizeof(float));
    u16* wqh  = (u16*)((char*)keepf + (size_t)NB * NH * SEQ * sizeof(float));
    u16* wql  = wqh + (size_t)3 * DMODEL * DMODEL;

    u16* xh = (u16*)d_out;                                        // d_out as scratch
    u16* xl = xh + (size_t)NB * SEQ * DMODEL;

    // 1) all precision conversions in one launch
    convert_all<<<(N8_X + N8_WQ + N8_WO + 255) / 256, 256, 0, stream>>>(
        x, xh, xl, w_qkv, wqh, wql, w_out, wob);

    // 2) QKV projection -> qh/ql (pre-scaled), kh/kl, vT (V tiles 1-term)
    gemm_split<0><<<768, 256, 0, stream>>>(xh, xl, wqh, wql, nullptr,
                                           qh, ql, kh, kl, vT, nullptr);

    // 3) softmax diagonal (LDS-shared K)
    dim3 gA(NB * NH, SEQ / 128);
    attn_pass1_mfma<<<gA, 256, 0, stream>>>(qh, ql, kh, kl, diag);

    // 4) z-score mask -> float 0/1
    mask_stats<<<NB * NH, 256, 0, stream>>>(diag, keepf);

    // 5) masked softmax + PV (LDS-shared K/V) -> att bf16 [b][tok][1024]
    attn_pass2_mfma<<<gA, 256, 0, stream>>>(qh, kh, vT, keepf, attb);

    // 6) output projection + bias
    gemm_split<1><<<256, 256, 0, stream>>>(attb, nullptr, wob, nullptr, b_out,
                                           nullptr, nullptr, nullptr, nullptr, nullptr, out);
}

// Round 8
// 172.738 us; speedup vs baseline: 1.2797x; 1.2797x over previous
//
#include <hip/hip_runtime.h>
#include <hip/hip_bf16.h>

#define NB 4
#define SEQ 1024
#define DMODEL 1024
#define NH 16
#define DH 64
#define SCALE_F 0.125f
#define QSCALE 0.18033688011112042f   // SCALE_F * log2(e): folds exp->exp2
#define ZTH 1.5f

typedef __bf16 bf16x8 __attribute__((ext_vector_type(8)));
typedef float f32x4 __attribute__((ext_vector_type(4)));
typedef unsigned short u16;
typedef unsigned int u32;

struct true_t  { static constexpr bool value = true;  };
struct false_t { static constexpr bool value = false; };

__device__ __forceinline__ u32 bf16_rne(float f) {
    u32 u = __float_as_uint(f);
    return (u + 0x7fffu + ((u >> 16) & 1u)) >> 16;
}
__device__ __forceinline__ u32 pk2(float a, float b) {   // low u16 = a
    return bf16_rne(a) | (bf16_rne(b) << 16);
}

// ---------------------------------------------------------------------------
// Fused precision-convert: x -> hi/lo, w_qkv -> hi/lo, w_out -> bf16.
// ---------------------------------------------------------------------------
#define N8_X   (NB * SEQ * DMODEL / 8)            // 524288
#define N8_WQ  (3 * DMODEL * DMODEL / 8)          // 393216
#define N8_WO  (DMODEL * DMODEL / 8)              // 131072

__global__ __launch_bounds__(256)
void convert_all(const float* __restrict__ x,  u16* __restrict__ xh,  u16* __restrict__ xl,
                 const float* __restrict__ wq, u16* __restrict__ wqh, u16* __restrict__ wql,
                 const float* __restrict__ wo, u16* __restrict__ wob)
{
    int i = blockIdx.x * 256 + threadIdx.x;
    const float* src;
    u16 *hi, *lo;
    int j;
    if (i < N8_X)              { src = x;  hi = xh;  lo = xl;  j = i; }
    else if (i < N8_X + N8_WQ) { src = wq; hi = wqh; lo = wql; j = i - N8_X; }
    else {
        j = i - N8_X - N8_WQ;
        if (j >= N8_WO) return;
        const float4* p = (const float4*)wo + (size_t)j * 2;
        float4 v0 = p[0], v1 = p[1];
        uint4 o;
        o.x = pk2(v0.x, v0.y); o.y = pk2(v0.z, v0.w);
        o.z = pk2(v1.x, v1.y); o.w = pk2(v1.z, v1.w);
        ((uint4*)wob)[j] = o;
        return;
    }
    const float4* p = (const float4*)src + (size_t)j * 2;
    float4 v0 = p[0], v1 = p[1];
    float f[8] = {v0.x, v0.y, v0.z, v0.w, v1.x, v1.y, v1.z, v1.w};
    u32 h[8], l[8];
    #pragma unroll
    for (int t = 0; t < 8; ++t) {
        u32 u = __float_as_uint(f[t]);
        u32 rh = (u + 0x7fffu + ((u >> 16) & 1u)) & 0xffff0000u;
        h[t] = rh >> 16;
        l[t] = bf16_rne(f[t] - __uint_as_float(rh));
    }
    uint4 ho, lw;
    ho.x = h[0] | (h[1] << 16); ho.y = h[2] | (h[3] << 16);
    ho.z = h[4] | (h[5] << 16); ho.w = h[6] | (h[7] << 16);
    lw.x = l[0] | (l[1] << 16); lw.y = l[2] | (l[3] << 16);
    lw.z = l[4] | (l[5] << 16); lw.w = l[6] | (l[7] << 16);
    ((uint4*)hi)[j] = ho;
    ((uint4*)lo)[j] = lw;
}

// ---------------------------------------------------------------------------
// MFMA GEMM: C = A * B^T, bf16 hi/lo split.
// MODE 0: QKV.  Q/K tiles run the 3-term K-loop; V tiles (nBase>=2048) run a
//         SEPARATE fully-constexpr 1-term K-loop (one top-level uniform
//         branch; no per-iteration conditionals -- R7's mistake).
// MODE 1: out-proj, 1-term; fp32 row-major + bias.
// ---------------------------------------------------------------------------
template<int MODE>
__global__ __launch_bounds__(256, 3)
void gemm_split(const u16* __restrict__ Ah, const u16* __restrict__ Al,
                const u16* __restrict__ Bh, const u16* __restrict__ Bl,
                const float* __restrict__ bias,
                u16* __restrict__ Qh, u16* __restrict__ Ql,
                u16* __restrict__ Kh, u16* __restrict__ Kl,
                u16* __restrict__ Vt, float* __restrict__ Cout)
{
    constexpr int M = NB * SEQ;
    constexpr int NCOL = (MODE == 0) ? 3 * DMODEL : DMODEL;
    constexpr int K = DMODEL;
    constexpr int NTN = NCOL / 128;
    constexpr int NWG = (M / 128) * NTN;
    constexpr int NT = (MODE == 0) ? 4 : 2;

    __shared__ u16 lds[NT][4][128][8];

    const int tid = threadIdx.x;
    const int bid = blockIdx.x;
    const int swz = (bid & 7) * (NWG >> 3) + (bid >> 3);
    const int mBase = (swz / NTN) * 128;
    const int nBase = (swz % NTN) * 128;

    const int wave = tid >> 6, lane = tid & 63;
    const int wr = wave >> 1, wc = wave & 1;
    const int rsel = lane & 15, ks = lane >> 4;

    const int r0 = tid >> 2, c0 = tid & 3;
    const size_t aoff0 = (size_t)(mBase + r0) * K + c0 * 8;
    const size_t aoff1 = (size_t)(mBase + 64 + r0) * K + c0 * 8;
    const size_t boff0 = (size_t)(nBase + r0) * K + c0 * 8;
    const size_t boff1 = (size_t)(nBase + 64 + r0) * K + c0 * 8;
    const int wrow0 = r0 ^ c0, wrow1 = (r0 ^ c0) + 64;

    const bf16x8 *rAh[4], *rAl[4], *rBh[4], *rBl[4];
    #pragma unroll
    for (int m = 0; m < 4; ++m) {
        int ar = (wr * 64 + m * 16 + rsel) ^ ks;
        rAh[m] = (const bf16x8*)&lds[0][ks][ar][0];
        if constexpr (MODE == 0) rAl[m] = (const bf16x8*)&lds[2][ks][ar][0];
    }
    #pragma unroll
    for (int n = 0; n < 4; ++n) {
        int bc = (wc * 64 + n * 16 + rsel) ^ ks;
        rBh[n] = (const bf16x8*)&lds[1][ks][bc][0];
        if constexpr (MODE == 0) rBl[n] = (const bf16x8*)&lds[3][ks][bc][0];
    }

    f32x4 acc[4][4];
    #pragma unroll
    for (int m = 0; m < 4; ++m)
        #pragma unroll
        for (int n = 0; n < 4; ++n)
            acc[m][n] = (f32x4)0.0f;

    // K-loop, fully specialized at compile time on T3 (3-term vs 1-term).
    auto kloop = [&](auto t3c) {
        constexpr bool T3 = decltype(t3c)::value;
        uint4 sAh0, sAh1, sAl0, sAl1, sBh0, sBh1, sBl0, sBl1;
        #define LOADS(k0)                                                   \
            sAh0 = *(const uint4*)(Ah + aoff0 + (k0));                      \
            sAh1 = *(const uint4*)(Ah + aoff1 + (k0));                      \
            sBh0 = *(const uint4*)(Bh + boff0 + (k0));                      \
            sBh1 = *(const uint4*)(Bh + boff1 + (k0));                      \
            if constexpr (T3) {                                             \
                sAl0 = *(const uint4*)(Al + aoff0 + (k0));                  \
                sAl1 = *(const uint4*)(Al + aoff1 + (k0));                  \
                sBl0 = *(const uint4*)(Bl + boff0 + (k0));                  \
                sBl1 = *(const uint4*)(Bl + boff1 + (k0));                  \
            }

        LOADS(0)
        for (int it = 0; it < K / 32; ++it) {
            __syncthreads();
            *(uint4*)&lds[0][c0][wrow0][0] = sAh0;
            *(uint4*)&lds[0][c0][wrow1][0] = sAh1;
            *(uint4*)&lds[1][c0][wrow0][0] = sBh0;
            *(uint4*)&lds[1][c0][wrow1][0] = sBh1;
            if constexpr (T3) {
                *(uint4*)&lds[2][c0][wrow0][0] = sAl0;
                *(uint4*)&lds[2][c0][wrow1][0] = sAl1;
                *(uint4*)&lds[3][c0][wrow0][0] = sBl0;
                *(uint4*)&lds[3][c0][wrow1][0] = sBl1;
            }
            __syncthreads();
            if (it < K / 32 - 1) {
                int k0 = (it + 1) * 32;
                LOADS(k0)
            }
            bf16x8 ah[4], bh[4], al[4], bl[4];
            #pragma unroll
            for (int m = 0; m < 4; ++m) { ah[m] = *rAh[m]; if constexpr (T3) al[m] = *rAl[m]; }
            #pragma unroll
            for (int n = 0; n < 4; ++n) { bh[n] = *rBh[n]; if constexpr (T3) bl[n] = *rBl[n]; }
            #pragma unroll
            for (int m = 0; m < 4; ++m)
                #pragma unroll
                for (int n = 0; n < 4; ++n) {
                    acc[m][n] = __builtin_amdgcn_mfma_f32_16x16x32_bf16(ah[m], bh[n], acc[m][n], 0, 0, 0);
                    if constexpr (T3) {
                        acc[m][n] = __builtin_amdgcn_mfma_f32_16x16x32_bf16(ah[m], bl[n], acc[m][n], 0, 0, 0);
                        acc[m][n] = __builtin_amdgcn_mfma_f32_16x16x32_bf16(al[m], bh[n], acc[m][n], 0, 0, 0);
                    }
                }
        }
        #undef LOADS
    };

    if constexpr (MODE == 0) {
        if (nBase < 2 * DMODEL) kloop(true_t{});   // Q/K: 3-term split
        else                    kloop(false_t{});  // V: 1-term (bf16-rounded anyway)
    } else {
        kloop(false_t{});
    }

    const int rowq = lane >> 4;
    #pragma unroll
    for (int m = 0; m < 4; ++m) {
        #pragma unroll
        for (int n = 0; n < 4; ++n) {
            int grow0 = mBase + wr * 64 + m * 16 + rowq * 4;
            int gcol  = nBase + wc * 64 + n * 16 + rsel;
            if constexpr (MODE == 0) {
                int which = gcol >> 10, h = (gcol >> 6) & 15, d = gcol & 63;
                if (which == 2) {
                    int b = grow0 >> 10, tok0 = grow0 & 1023;
                    ushort4 vv;
                    vv.x = (u16)bf16_rne(acc[m][n][0]);
                    vv.y = (u16)bf16_rne(acc[m][n][1]);
                    vv.z = (u16)bf16_rne(acc[m][n][2]);
                    vv.w = (u16)bf16_rne(acc[m][n][3]);
                    *(ushort4*)&Vt[((size_t)(b * NH + h) * DH + d) * SEQ + tok0] = vv;
                } else {
                    u16* Ph = (which == 0) ? Qh : Kh;
                    u16* Pl = (which == 0) ? Ql : Kl;
                    const float sc = (which == 0) ? QSCALE : 1.0f;
                    #pragma unroll
                    for (int r = 0; r < 4; ++r) {
                        int grow = grow0 + r;
                        int b = grow >> 10, tok = grow & 1023;
                        size_t idx = ((size_t)(b * NH + h) * SEQ + tok) * DH + d;
                        float f = acc[m][n][r] * sc;
                        u32 u = __float_as_uint(f);
                        u32 rh = (u + 0x7fffu + ((u >> 16) & 1u)) & 0xffff0000u;
                        Ph[idx] = (u16)(rh >> 16);
                        Pl[idx] = (u16)bf16_rne(f - __uint_as_float(rh));
                    }
                }
            } else {
                float bb = bias[gcol];
                #pragma unroll
                for (int r = 0; r < 4; ++r)
                    Cout[(size_t)(grow0 + r) * NCOL + gcol] = acc[m][n][r] + bb;
            }
        }
    }
}

// ---------------------------------------------------------------------------
// Pass 1 (R6): diag of softmax(dots), LDS-shared K chunks.
// ---------------------------------------------------------------------------
__global__ __launch_bounds__(256)
void attn_pass1_mfma(const u16* __restrict__ qhp, const u16* __restrict__ qlp,
                     const u16* __restrict__ khp, const u16* __restrict__ klp,
                     float* __restrict__ diag)
{
    __shared__ u16 Ks[64][64];
    __shared__ u16 Kl[64][64];
    const int bh = blockIdx.x;
    const int tid = threadIdx.x;
    const int wid = tid >> 6, lane = tid & 63;
    const int qloc = lane & 15, quad = lane >> 4;
    const int qbase = blockIdx.y * 128 + wid * 32;
    const size_t base = (size_t)bh * SEQ;

    bf16x8 qbh[2][2], qbl[2][2];
    #pragma unroll
    for (int qf = 0; qf < 2; ++qf)
        #pragma unroll
        for (int dc = 0; dc < 2; ++dc) {
            size_t off = (base + qbase + qf * 16 + qloc) * DH + dc * 32 + quad * 8;
            qbh[qf][dc] = *(const bf16x8*)(qhp + off);
            qbl[qf][dc] = *(const bf16x8*)(qlp + off);
        }

    const int r0 = tid >> 3, s0 = tid & 7, r1 = r0 + 32;
    const int ws0 = (s0 ^ (r0 & 7)) * 8;
    const int ws1 = (s0 ^ (r1 & 7)) * 8;
    const u16* kb = khp + base * DH;
    const u16* lb = klp + base * DH;

    int aoff[4][2];
    #pragma unroll
    for (int t = 0; t < 4; ++t)
        #pragma unroll
        for (int dc = 0; dc < 2; ++dc)
            aoff[t][dc] = (t * 16 + qloc) * 128 + (((dc * 4 + quad) ^ (qloc & 7)) << 4);

    float lsum[2] = {0.f, 0.f}, sd[2] = {0.f, 0.f};
    const int dcb  = qbase & ~63;
    const int toff = (qbase & 32) >> 4;

    uint4 gk0, gk1, gl0, gl1;
    #define P1LOAD(cb)                                                      \
        gk0 = *(const uint4*)(kb + (size_t)((cb) + r0) * DH + s0 * 8);      \
        gk1 = *(const uint4*)(kb + (size_t)((cb) + r1) * DH + s0 * 8);      \
        gl0 = *(const uint4*)(lb + (size_t)((cb) + r0) * DH + s0 * 8);      \
        gl1 = *(const uint4*)(lb + (size_t)((cb) + r1) * DH + s0 * 8);

    P1LOAD(0)
    for (int it = 0; it < SEQ / 64; ++it) {
        __syncthreads();
        *(uint4*)&Ks[r0][ws0] = gk0;
        *(uint4*)&Ks[r1][ws1] = gk1;
        *(uint4*)&Kl[r0][ws0] = gl0;
        *(uint4*)&Kl[r1][ws1] = gl1;
        __syncthreads();
        if (it < SEQ / 64 - 1) { P1LOAD((it + 1) * 64) }

        const int cb = it * 64;
        const bool dchunk = (cb == dcb);
        bf16x8 ah[4][2], al[4][2];
        #pragma unroll
        for (int t = 0; t < 4; ++t)
            #pragma unroll
            for (int dc = 0; dc < 2; ++dc) {
                ah[t][dc] = *(const bf16x8*)((const char*)&Ks[0][0] + aoff[t][dc]);
                al[t][dc] = *(const bf16x8*)((const char*)&Kl[0][0] + aoff[t][dc]);
            }
        #pragma unroll
        for (int qf = 0; qf < 2; ++qf)
            #pragma unroll
            for (int t = 0; t < 4; ++t) {
                f32x4 d = (f32x4)0.f;
                #pragma unroll
                for (int dc = 0; dc < 2; ++dc) {
                    d = __builtin_amdgcn_mfma_f32_16x16x32_bf16(ah[t][dc], qbh[qf][dc], d, 0, 0, 0);
                    d = __builtin_amdgcn_mfma_f32_16x16x32_bf16(ah[t][dc], qbl[qf][dc], d, 0, 0, 0);
                    d = __builtin_amdgcn_mfma_f32_16x16x32_bf16(al[t][dc], qbh[qf][dc], d, 0, 0, 0);
                }
                if (dchunk) {
                    #pragma unroll
                    for (int dc = 0; dc < 2; ++dc)
                        d = __builtin_amdgcn_mfma_f32_16x16x32_bf16(al[t][dc], qbl[qf][dc], d, 0, 0, 0);
                }
                #pragma unroll
                for (int r = 0; r < 4; ++r) {
                    float ex = exp2f(d[r]);
                    lsum[qf] += ex;
                    if (dchunk && t == toff + qf && quad == (qloc >> 2) && r == (qloc & 3))
                        sd[qf] = ex;
                }
            }
    }
    #undef P1LOAD

    #pragma unroll
    for (int qf = 0; qf < 2; ++qf) {
        lsum[qf] += __shfl_xor(lsum[qf], 16);
        lsum[qf] += __shfl_xor(lsum[qf], 32);
        sd[qf]   += __shfl_xor(sd[qf], 16);
        sd[qf]   += __shfl_xor(sd[qf], 32);
    }
    if (quad == 0) {
        diag[base + qbase + qloc]      = sd[0] / lsum[0];
        diag[base + qbase + 16 + qloc] = sd[1] / lsum[1];
    }
}

// ---------------------------------------------------------------------------
// Per-(b,h) z-score mask -> float 0/1 (unchanged).
// ---------------------------------------------------------------------------
__global__ __launch_bounds__(256)
void mask_stats(const float* __restrict__ diag, float* __restrict__ keepf)
{
    __shared__ float red[256];
    const int bh = blockIdx.x, tid = threadIdx.x;
    const float* d = diag + (size_t)bh * SEQ;
    float4 v = *(const float4*)(d + tid * 4);
    red[tid] = (v.x + v.y) + (v.z + v.w);
    __syncthreads();
    for (int w = 128; w > 0; w >>= 1) {
        if (tid < w) red[tid] += red[tid + w];
        __syncthreads();
    }
    float mu = red[0] * (1.0f / 1024.0f);
    __syncthreads();
    float dx0 = v.x - mu, dx1 = v.y - mu, dx2 = v.z - mu, dx3 = v.w - mu;
    red[tid] = (dx0 * dx0 + dx1 * dx1) + (dx2 * dx2 + dx3 * dx3);
    __syncthreads();
    for (int w = 128; w > 0; w >>= 1) {
        if (tid < w) red[tid] += red[tid + w];
        __syncthreads();
    }
    float sd = sqrtf(red[0] * (1.0f / 1023.0f));
    float4 kv;
    kv.x = (fabsf(dx0 / sd) <= ZTH) ? 1.f : 0.f;
    kv.y = (fabsf(dx1 / sd) <= ZTH) ? 1.f : 0.f;
    kv.z = (fabsf(dx2 / sd) <= ZTH) ? 1.f : 0.f;
    kv.w = (fabsf(dx3 / sd) <= ZTH) ? 1.f : 0.f;
    *(float4*)&keepf[(size_t)bh * SEQ + tid * 4] = kv;
}

// ---------------------------------------------------------------------------
// Pass 2 (R6): masked softmax + PV, LDS-shared K/V chunks.
// ---------------------------------------------------------------------------
__global__ __launch_bounds__(256)
void attn_pass2_mfma(const u16* __restrict__ qhp, const u16* __restrict__ khp,
                     const u16* __restrict__ vTp, const float* __restrict__ keepf,
                     u16* __restrict__ att)
{
    __shared__ u16 Ks[64][64];
    __shared__ u16 Vs[64][64];
    __shared__ u16 P[4][32][64];
    const int bh = blockIdx.x;
    const int b = bh >> 4, h = bh & 15;
    const int tid = threadIdx.x;
    const int wid = tid >> 6, lane = tid & 63;
    const int qloc = lane & 15, quad = lane >> 4;
    const int qbase = blockIdx.y * 128 + wid * 32;
    const size_t base = (size_t)bh * SEQ;

    bf16x8 qb[2][2];
    #pragma unroll
    for (int qf = 0; qf < 2; ++qf)
        #pragma unroll
        for (int dc = 0; dc < 2; ++dc)
            qb[qf][dc] = *(const bf16x8*)(qhp + (base + qbase + qf * 16 + qloc) * DH + dc * 32 + quad * 8);

    const float rkf[2] = {keepf[base + qbase + qloc],
                          keepf[base + qbase + 16 + qloc]};

    const int r0 = tid >> 3, s0 = tid & 7, r1 = r0 + 32;
    const int ws0 = (s0 ^ (r0 & 7)) * 8;
    const int ws1 = (s0 ^ (r1 & 7)) * 8;
    const u16* kb = khp + base * DH;
    const u16* vb = vTp + (size_t)bh * DH * SEQ;

    int aoff[4][2], voff[4][2];
    #pragma unroll
    for (int t = 0; t < 4; ++t)
        #pragma unroll
        for (int dc = 0; dc < 2; ++dc)
            aoff[t][dc] = (t * 16 + qloc) * 128 + (((dc * 4 + quad) ^ (qloc & 7)) << 4);
    #pragma unroll
    for (int dt = 0; dt < 4; ++dt)
        #pragma unroll
        for (int c = 0; c < 2; ++c)
            voff[dt][c] = (dt * 16 + qloc) * 128 + (((c * 4 + quad) ^ (qloc & 7)) << 4);

    char* Pw = (char*)&P[wid][0][0];
    int woff[2][4], roff[2][2];
    #pragma unroll
    for (int qf = 0; qf < 2; ++qf) {
        int row = qf * 16 + qloc;
        #pragma unroll
        for (int t = 0; t < 4; ++t) {
            int g = t * 2 + (quad >> 1);
            woff[qf][t] = row * 128 + ((g ^ (qloc & 7)) << 4) + (quad & 1) * 8;
        }
        #pragma unroll
        for (int c = 0; c < 2; ++c) {
            int g = c * 4 + quad;
            roff[qf][c] = row * 128 + ((g ^ (qloc & 7)) << 4);
        }
    }

    f32x4 acc2[2][4];
    #pragma unroll
    for (int qf = 0; qf < 2; ++qf)
        #pragma unroll
        for (int dt = 0; dt < 4; ++dt)
            acc2[qf][dt] = (f32x4)0.f;
    float lsum[2] = {0.f, 0.f};

    uint4 gk0, gk1, gv0, gv1;
    #define P2LOAD(cb)                                                      \
        gk0 = *(const uint4*)(kb + (size_t)((cb) + r0) * DH + s0 * 8);      \
        gk1 = *(const uint4*)(kb + (size_t)((cb) + r1) * DH + s0 * 8);      \
        gv0 = *(const uint4*)(vb + (size_t)r0 * SEQ + (cb) + s0 * 8);       \
        gv1 = *(const uint4*)(vb + (size_t)r1 * SEQ + (cb) + s0 * 8);

    P2LOAD(0)
    for (int it = 0; it < SEQ / 64; ++it) {
        __syncthreads();
        *(uint4*)&Ks[r0][ws0] = gk0;
        *(uint4*)&Ks[r1][ws1] = gk1;
        *(uint4*)&Vs[r0][ws0] = gv0;
        *(uint4*)&Vs[r1][ws1] = gv1;
        __syncthreads();
        if (it < SEQ / 64 - 1) { P2LOAD((it + 1) * 64) }

        const int cb = it * 64;
        bf16x8 ah[4][2], va[4][2];
        #pragma unroll
        for (int t = 0; t < 4; ++t)
            #pragma unroll
            for (int dc = 0; dc < 2; ++dc)
                ah[t][dc] = *(const bf16x8*)((const char*)&Ks[0][0] + aoff[t][dc]);
        #pragma unroll
        for (int dt = 0; dt < 4; ++dt)
            #pragma unroll
            for (int c = 0; c < 2; ++c)
                va[dt][c] = *(const bf16x8*)((const char*)&Vs[0][0] + voff[dt][c]);

        float4 kf[4];
        #pragma unroll
        for (int t = 0; t < 4; ++t)
            kf[t] = *(const float4*)(keepf + base + cb + t * 16 + quad * 4);

        #pragma unroll
        for (int qf = 0; qf < 2; ++qf)
            #pragma unroll
            for (int t = 0; t < 4; ++t) {
                f32x4 d = (f32x4)0.f;
                d = __builtin_amdgcn_mfma_f32_16x16x32_bf16(ah[t][0], qb[qf][0], d, 0, 0, 0);
                d = __builtin_amdgcn_mfma_f32_16x16x32_bf16(ah[t][1], qb[qf][1], d, 0, 0, 0);
                float p0 = exp2f(d[0]) * kf[t].x;
                float p1 = exp2f(d[1]) * kf[t].y;
                float p2 = exp2f(d[2]) * kf[t].z;
                float p3 = exp2f(d[3]) * kf[t].w;
                lsum[qf] += (p0 + p1) + (p2 + p3);
                uint2 w;
                asm("v_cvt_pk_bf16_f32 %0, %1, %2" : "=v"(w.x) : "v"(p0), "v"(p1));
                asm("v_cvt_pk_bf16_f32 %0, %1, %2" : "=v"(w.y) : "v"(p2), "v"(p3));
                *(uint2*)(Pw + woff[qf][t]) = w;
            }

        #pragma unroll
        for (int qf = 0; qf < 2; ++qf) {
            #pragma unroll
            for (int c = 0; c < 2; ++c) {
                bf16x8 pb = *(const bf16x8*)(Pw + roff[qf][c]);
                #pragma unroll
                for (int dt = 0; dt < 4; ++dt)
                    acc2[qf][dt] = __builtin_amdgcn_mfma_f32_16x16x32_bf16(va[dt][c], pb, acc2[qf][dt], 0, 0, 0);
            }
        }
    }
    #undef P2LOAD

    #pragma unroll
    for (int qf = 0; qf < 2; ++qf) {
        lsum[qf] += __shfl_xor(lsum[qf], 16);
        lsum[qf] += __shfl_xor(lsum[qf], 32);
        float inv = rkf[qf] / fmaxf(lsum[qf], 1e-30f);
        int tok = qbase + qf * 16 + qloc;
        #pragma unroll
        for (int dt = 0; dt < 4; ++dt) {
            uint2 w;
            w.x = pk2(acc2[qf][dt][0] * inv, acc2[qf][dt][1] * inv);
            w.y = pk2(acc2[qf][dt][2] * inv, acc2[qf][dt][3] * inv);
            *(uint2*)&att[((size_t)(b * SEQ + tok)) * DMODEL + h * DH + dt * 16 + quad * 4] = w;
        }
    }
}

// ---------------------------------------------------------------------------
extern "C" void kernel_launch(void* const* d_in, const int* in_sizes, int n_in,
                              void* d_out, int out_size, void* d_ws, size_t ws_size,
                              hipStream_t stream)
{
    const float* x     = (const float*)d_in[0];
    const float* w_qkv = (const float*)d_in[1];
    const float* w_out = (const float*)d_in[2];
    const float* b_out = (const float*)d_in[3];
    float* out = (float*)d_out;

    char* ws = (char*)d_ws;
    const size_t T = (size_t)NB * NH * SEQ * DH * sizeof(u16);   // 8 MB per head-tensor

    u16* qh   = (u16*)(ws);
    u16* ql   = (u16*)(ws + T);
    u16* kh   = (u16*)(ws + 2 * T);
    u16* kl   = (u16*)(ws + 3 * T);
    u16* vT   = (u16*)(ws + 4 * T);
    u16* attb = (u16*)(ws + 5 * T);
    u16* wob  = (u16*)(ws + 6 * T);                               // 2 MB
    float* diag  = (float*)(ws + 6 * T + (size_t)DMODEL * DMODEL * sizeof(u16));
    float* keepf = (float*)((char*)diag + (size_t)NB * NH * SEQ * sizeof(float));
    u16* wqh  = (u16*)((char*)keepf + (size_t)NB * NH * SEQ * sizeof(float));
    u16* wql  = wqh + (size_t)3 * DMODEL * DMODEL;

    u16* xh = (u16*)d_out;                                        // d_out as scratch
    u16* xl = xh + (size_t)NB * SEQ * DMODEL;

    // 1) all precision conversions in one launch
    convert_all<<<(N8_X + N8_WQ + N8_WO + 255) / 256, 256, 0, stream>>>(
        x, xh, xl, w_qkv, wqh, wql, w_out, wob);

    // 2) QKV projection -> qh/ql (pre-scaled), kh/kl, vT (V blocks 1-term)
    gemm_split<0><<<768, 256, 0, stream>>>(xh, xl, wqh, wql, nullptr,
                                           qh, ql, kh, kl, vT, nullptr);

    // 3) softmax diagonal (LDS-shared K)
    dim3 gA(NB * NH, SEQ / 128);
    attn_pass1_mfma<<<gA, 256, 0, stream>>>(qh, ql, kh, kl, diag);

    // 4) z-score mask -> float 0/1
    mask_stats<<<NB * NH, 256, 0, stream>>>(diag, keepf);

    // 5) masked softmax + PV (LDS-shared K/V) -> att bf16 [b][tok][1024]
    attn_pass2_mfma<<<gA, 256, 0, stream>>>(qh, kh, vT, keepf, attb);

    // 6) output projection + bias
    gemm_split<1><<<256, 256, 0, stream>>>(attb, nullptr, wob, nullptr, b_out,
                                           nullptr, nullptr, nullptr, nullptr, nullptr, out);
}